// Round 4
// baseline (554.081 us; speedup 1.0000x reference)
//
#include <hip/hip_runtime.h>

typedef short v8s __attribute__((ext_vector_type(8)));
typedef _Float16 v8h __attribute__((ext_vector_type(8)));
typedef float v4f __attribute__((ext_vector_type(4)));

#define BMT 128
#define BNT 128
#define BKT 32

__device__ __forceinline__ unsigned short f2bf(float f) {
    unsigned int u = __float_as_uint(f);
    u += 0x7fff + ((u >> 16) & 1);   // RNE
    return (unsigned short)(u >> 16);
}
__device__ __forceinline__ unsigned short f2h(float f) {
    union { _Float16 h; unsigned short u; } c;
    c.h = (_Float16)f;
    return c.u;
}
__device__ __forceinline__ float h2f(unsigned short v) {
    union { unsigned short u; _Float16 h; } c;
    c.u = v;
    return (float)c.h;
}
__device__ __forceinline__ v8h as_h(v8s x) {
    union { v8s s; v8h h; } c;
    c.s = x;
    return c.h;
}

union U128 { unsigned short s[8]; uint4 v; };

// async 16B global -> LDS (wave-uniform LDS base + lane*16 implicit)
__device__ __forceinline__ void gld16(const unsigned short* g, unsigned short* l) {
    __builtin_amdgcn_global_load_lds((const __attribute__((address_space(1))) void*)g,
                                     (__attribute__((address_space(3))) void*)l, 16, 0, 0);
}

// ---------------------------------------------------------------------------
// fp32 -> bf16 plane (adj)
__global__ __launch_bounds__(256) void split_hi(const float* __restrict__ x,
                                                unsigned short* __restrict__ oh, int n4) {
    int i = blockIdx.x * 256 + threadIdx.x;
    if (i < n4) {
        float4 f = ((const float4*)x)[i];
        float fv[4] = {f.x, f.y, f.z, f.w};
        ushort4 h;
        unsigned short* hp = (unsigned short*)&h;
#pragma unroll
        for (int j = 0; j < 4; ++j) hp[j] = f2bf(fv[j]);
        ((ushort4*)oh)[i] = h;
    }
}

// transpose-convert: W fp32 [R][C] -> WT f16 [C][R], 64x64 LDS tiles.
// Both global read and write fully coalesced (old version scattered 2B
// writes at stride 2*R -> 32x write amplification).
__global__ __launch_bounds__(256) void tsplit16(const float* __restrict__ W,
                                                unsigned short* __restrict__ th, int R, int C) {
    __shared__ unsigned short lds[64][80];   // [c][r], padded to 160B rows
    const int t = threadIdx.x;
    const int rt = blockIdx.x, ct = blockIdx.y;
    const int r = t >> 2, c0 = (t & 3) * 16;
    const float* src = W + (size_t)(rt * 64 + r) * C + ct * 64 + c0;
#pragma unroll
    for (int j = 0; j < 16; j += 4) {
        float4 f = *(const float4*)(src + j);
        lds[c0 + j + 0][r] = f2h(f.x);
        lds[c0 + j + 1][r] = f2h(f.y);
        lds[c0 + j + 2][r] = f2h(f.z);
        lds[c0 + j + 3][r] = f2h(f.w);
    }
    __syncthreads();
    const int c = t >> 2, r0 = (t & 3) * 16;
    U128 u0, u1;
#pragma unroll
    for (int j = 0; j < 8; ++j) { u0.s[j] = lds[c][r0 + j]; u1.s[j] = lds[c][r0 + 8 + j]; }
    unsigned short* dst = th + (size_t)(ct * 64 + c) * R + rt * 64 + r0;
    *(uint4*)dst = u0.v;
    *(uint4*)(dst + 8) = u1.v;
}

// ---------------------------------------------------------------------------
// Fused x preprocessing (reads x fp32 ONCE):
//   X16 f16 [z*1024+node][256]  (dense1 A operand)
//   Th  bf16 [z*256+f][1024]    (agg1 B operand, transposed)
__global__ __launch_bounds__(256) void xprep(const float* __restrict__ src,
                                             unsigned short* __restrict__ th,
                                             unsigned short* __restrict__ x16, int d) {
    __shared__ unsigned int lds[64 * 66];
    const int t = threadIdx.x;
    const int mt = blockIdx.x, ft = blockIdx.y, z = blockIdx.z;
    const int r = t >> 3, c8 = (t & 7) * 8;
#pragma unroll
    for (int half = 0; half < 2; ++half) {
        int rr = r + half * 32;
        size_t grow = (size_t)z * 1024 + mt * 64 + rr;
        const float* xs = src + grow * d + ft * 64 + c8;
        float4 f0 = *(const float4*)xs;
        float4 f1 = *(const float4*)(xs + 4);
        float fv[8] = {f0.x, f0.y, f0.z, f0.w, f1.x, f1.y, f1.z, f1.w};
        U128 uh;
#pragma unroll
        for (int j = 0; j < 8; ++j) {
            lds[rr * 66 + c8 + j] = f2bf(fv[j]);
            uh.s[j] = f2h(fv[j]);
        }
        *(uint4*)(x16 + grow * d + ft * 64 + c8) = uh.v;
    }
    __syncthreads();
    const int f = t >> 3, m0 = (t & 7) * 8;
#pragma unroll
    for (int half = 0; half < 2; ++half) {
        int ff = f + half * 32;
        U128 uh;
#pragma unroll
        for (int j = 0; j < 8; ++j)
            uh.s[j] = (unsigned short)lds[(m0 + j) * 66 + ff];
        size_t orow = ((size_t)z * d + ft * 64 + ff) * 1024 + mt * 64 + m0;
        *(uint4*)(th + orow) = uh.v;
    }
}

// ---------------------------------------------------------------------------
// Legacy 128x128x32 GEMM (m97-structure) — kept only for the fp32-adj fallback.
template <int ACT, bool TWO, int AMODE, int DT, bool WRT>
__global__ __launch_bounds__(256) void gemm128(
    const void* a1, const unsigned short* __restrict__ a2,
    int K1, int K2,
    const unsigned short* __restrict__ b_, int ldb,
    const float* __restrict__ bias, const float* __restrict__ alpha,
    unsigned short* __restrict__ o_, int Nout,
    unsigned short* __restrict__ th,
    size_t aZ, size_t bZ, int cZRows,
    int nblk, int mBits)
{
    constexpr int LA = (AMODE == 0) ? 32 : 40;
    constexpr int LB = 32;
    __shared__ __align__(16) unsigned short Ash[BMT * LA];
    __shared__ __align__(16) unsigned short Bsh[BNT * LB];

    const int t = threadIdx.x;
    const int lane = t & 63, wave = t >> 6;
    const int wm = wave >> 1, wn = wave & 1;
    const int l15 = lane & 15, quad = lane >> 4;

    const int bx = blockIdx.x;
    const int low3 = bx & 7, rest = bx >> 3;
    const int nIdx = rest % nblk, g = rest / nblk;
    const int grp = g * 8 + low3;
    const int m0 = (grp & ((1 << mBits) - 1)) * BMT;
    const int zb = grp >> mBits;
    const int n0 = nIdx * BNT;

    const unsigned short* bhz = b_ + (size_t)zb * bZ;

    v4f acc[4][4] = {};

    const int nch = TWO ? 2 : 1;
    for (int ch = 0; ch < nch; ++ch) {
        const int K = (TWO && ch) ? K2 : K1;
        const int kr0 = (TWO && ch) ? K1 : 0;
        const unsigned short* ah = nullptr;
        const float* af = nullptr;
        if constexpr (AMODE == 0)
            ah = (ch ? a2 : (const unsigned short*)a1) + (size_t)zb * aZ;
        else
            af = (const float*)a1 + (size_t)zb * aZ;

        for (int kk = 0; kk < K; kk += BKT) {
            __syncthreads();
            if constexpr (AMODE == 0) {
#pragma unroll
                for (int i = 0; i < 2; ++i) {
                    int s = i * 256 + t;
                    int row = s >> 2;
                    int cg = (s & 3) ^ ((s >> 3) & 3);
                    size_t go = (size_t)(m0 + row) * K + kk + cg * 8;
                    int ls = (i * 256 + (t & ~63)) * 8;
                    gld16(ah + go, &Ash[ls]);
                }
            } else {
#pragma unroll
                for (int i = 0; i < 2; ++i) {
                    int cid = i * 256 + t;
                    int row = cid >> 2, c = cid & 3;
                    const float* src = af + (size_t)(m0 + row) * K + kk + c * 8;
                    float4 f0 = *(const float4*)src;
                    float4 f1 = *(const float4*)(src + 4);
                    float fv[8] = {f0.x, f0.y, f0.z, f0.w, f1.x, f1.y, f1.z, f1.w};
                    U128 uh;
#pragma unroll
                    for (int j = 0; j < 8; ++j) uh.s[j] = f2bf(fv[j]);
                    *(uint4*)&Ash[row * LA + c * 8] = uh.v;
                }
            }
#pragma unroll
            for (int i = 0; i < 2; ++i) {
                int s = i * 256 + t;
                int row = s >> 2;
                int cg = (s & 3) ^ ((s >> 3) & 3);
                size_t go = (size_t)(n0 + row) * ldb + kr0 + kk + cg * 8;
                int ls = (i * 256 + (t & ~63)) * 8;
                gld16(bhz + go, &Bsh[ls]);
            }
            __syncthreads();
            v8s ahf[4];
#pragma unroll
            for (int mi = 0; mi < 4; ++mi) {
                int row = wm * 64 + mi * 16 + l15;
                int off;
                if constexpr (AMODE == 0) off = row * LA + ((quad ^ ((row >> 1) & 3)) * 8);
                else                      off = row * LA + quad * 8;
                ahf[mi] = *(const v8s*)&Ash[off];
            }
#pragma unroll
            for (int ni = 0; ni < 4; ++ni) {
                int row = wn * 64 + ni * 16 + l15;
                int off = row * LB + ((quad ^ ((row >> 1) & 3)) * 8);
                v8s bhf = *(const v8s*)&Bsh[off];
#pragma unroll
                for (int mi = 0; mi < 4; ++mi) {
                    if constexpr (DT == 0)
                        acc[mi][ni] = __builtin_amdgcn_mfma_f32_16x16x32_bf16(ahf[mi], bhf, acc[mi][ni], 0, 0, 0);
                    else
                        acc[mi][ni] = __builtin_amdgcn_mfma_f32_16x16x32_f16(as_h(ahf[mi]), as_h(bhf), acc[mi][ni], 0, 0, 0);
                }
            }
        }
    }

    const size_t crow0 = (size_t)zb * cZRows + m0;
#pragma unroll
    for (int ni = 0; ni < 4; ++ni) {
        int n = n0 + wn * 64 + ni * 16 + l15;
        float bv = (ACT > 0) ? bias[n] : 0.f;
        float av = (ACT == 2) ? alpha[n] : 0.f;
#pragma unroll
        for (int mi = 0; mi < 4; ++mi) {
#pragma unroll
            for (int r = 0; r < 4; ++r) {
                int m = wm * 64 + mi * 16 + quad * 4 + r;
                float v = acc[mi][ni][r] + bv;
                if (ACT == 1) v = v > 0.f ? v : 0.f;
                if (ACT == 2) v = v > 0.f ? v : av * v;
                acc[mi][ni][r] = v;
                o_[(crow0 + m) * (size_t)Nout + n] = f2h(v);
            }
        }
    }

    if constexpr (WRT) {
        const int zbT = m0 >> 10;
        const int mloc0 = (m0 & 1023) + wm * 64;
#pragma unroll
        for (int ni = 0; ni < 4; ++ni) {
            int f = n0 + wn * 64 + ni * 16 + l15;
            size_t rowb = (((size_t)zbT * Nout + f) << 10) + mloc0;
#pragma unroll
            for (int mi = 0; mi < 4; ++mi) {
                ushort4 u;
                unsigned short* up = (unsigned short*)&u;
#pragma unroll
                for (int r = 0; r < 4; ++r) up[r] = f2bf(acc[mi][ni][r]);
                *(ushort4*)(th + rowb + mi * 16 + quad * 4) = u;
            }
        }
    }
}

// ---------------------------------------------------------------------------
// 256-wide phase-interleaved GEMM (T2/T3/T4/T5 stack, m201-style phases over
// the proven ring-4 skeleton).
//   BM = 256, BN2 in {128, 256}. BK = 32. 512 threads = 8 waves.
//   Per K-tile: NPH phases (4 for BN=256, 2 for BN=128); each phase =
//   {ds_read 2 A-frags (+B on q0), issue 1/NPH of tile(t+3)'s staging,
//    s_barrier, setprio(1), 8 MFMAs, setprio(0)}.
//   One counted s_waitcnt vmcnt(LPT) + barrier per K-tile — never 0 mid-loop.
// Race-freedom (identical to prior rounds): stage(t+3) writes slot (t-1)&3;
// all reads of that slot were lgkmcnt-drained before the previous iter
// barrier, and the barrier orders them before any wave issues the writes.
// vmcnt oldest-first: with {t+2,t+3} in flight (2*LPT), vmcnt(LPT) <=> t+2
// fully landed (one tile early).
template <int ACT, bool TWO, int DT, bool WRT, int BN2>
__global__ __launch_bounds__(512, 2) void gemm256(
    const unsigned short* __restrict__ a1, const unsigned short* __restrict__ a2,
    int K1, int K2,
    const unsigned short* __restrict__ b_, int ldb,
    const float* __restrict__ bias, const float* __restrict__ alpha,
    unsigned short* __restrict__ o_, int Nout,
    unsigned short* __restrict__ th,
    size_t aZ, size_t bZ, int cZRows,
    int nblk, int mBits)
{
    constexpr int ASLOT = 256 * 32;          // ushorts per A K-tile
    constexpr int BSLOT = BN2 * 32;
    constexpr int SLOT  = ASLOT + BSLOT;
    constexpr int LPT   = 2 + BN2 / 128;     // gld16 per thread per K-tile (4 or 3)
    constexpr int WN    = BN2 / 64;          // waves along N (4 or 2)
    constexpr int WM    = 8 / WN;            // waves along M (2 or 4)
    constexpr int MREP  = 16 / WM;           // 16x16 frags along M per wave (8 or 4)
    constexpr int NPH   = MREP / 2;          // phases per K-tile (4 or 2)
    __shared__ __align__(16) unsigned short lds[4 * SLOT];

    const int t = threadIdx.x;
    const int lane = t & 63, wave = t >> 6;
    const int wm = wave / WN, wn = wave % WN;
    const int l15 = lane & 15, quad = lane >> 4;

    // swizzled grid decode (all grids %8==0)
    const int bx = blockIdx.x;
    const int low3 = bx & 7, rest = bx >> 3;
    const int nIdx = rest % nblk, g = rest / nblk;
    const int grp = g * 8 + low3;
    const int m0 = (grp & ((1 << mBits) - 1)) * 256;
    const int zb = grp >> mBits;
    const int n0 = nIdx * BN2;

    const unsigned short* A1 = a1 + (size_t)zb * aZ;
    const unsigned short* A2p = TWO ? (a2 + (size_t)zb * aZ) : nullptr;
    const unsigned short* B = b_ + (size_t)zb * bZ;

    const int NT1 = K1 >> 5;
    const int NTtot = NT1 + (TWO ? (K2 >> 5) : 0);   // >= 8

    // issue part p (0..NPH-1) of tile tt's staging: 1 gld16 (BN=256) or
    // {2,1} gld16 (BN=128)
    auto stage_part = [&](int tt, int p) {
        unsigned short* slot = &lds[(tt & 3) * SLOT];
        const unsigned short* abase;
        int astr;
        if constexpr (TWO) {
            if (tt >= NT1) { abase = A2p + ((size_t)(tt - NT1) << 5); astr = K2; }
            else           { abase = A1 + ((size_t)tt << 5); astr = K1; }
        } else {
            abase = A1 + ((size_t)tt << 5); astr = K1;
        }
        auto lda = [&](int i) {
            int s = i * 512 + t;
            int row = s >> 2;
            int cg = (s & 3) ^ ((s >> 3) & 3);            // read-side-matched swizzle
            gld16(abase + (size_t)(m0 + row) * astr + cg * 8,
                  &slot[(i * 512 + (t & ~63)) * 8]);
        };
        auto ldb_ = [&](int i) {
            const unsigned short* bbase = B + ((size_t)tt << 5);
            int s = i * 512 + t;
            int row = s >> 2;
            int cg = (s & 3) ^ ((s >> 3) & 3);
            gld16(bbase + (size_t)(n0 + row) * ldb + cg * 8,
                  &slot[ASLOT + (i * 512 + (t & ~63)) * 8]);
        };
        if constexpr (BN2 == 256) {
            if (p < 2) lda(p); else ldb_(p - 2);
        } else {
            if (p == 0) { lda(0); lda(1); } else ldb_(0);
        }
    };
    auto stage_all = [&](int tt) {
#pragma unroll
        for (int p = 0; p < NPH; ++p) stage_part(tt, p);
    };

    v4f acc[MREP][4] = {};

    auto rdA = [&](const unsigned short* slot, int mi) -> v8s {
        int row = wm * (MREP * 16) + mi * 16 + l15;
        return *(const v8s*)&slot[row * 32 + ((quad ^ ((row >> 1) & 3)) * 8)];
    };
    auto rdB = [&](const unsigned short* slot, int ni) -> v8s {
        int row = wn * 64 + ni * 16 + l15;
        return *(const v8s*)&slot[ASLOT + row * 32 + ((quad ^ ((row >> 1) & 3)) * 8)];
    };

    auto wait_lpt = [&]() {
        if constexpr (LPT == 4) asm volatile("s_waitcnt vmcnt(4)" ::: "memory");
        else                    asm volatile("s_waitcnt vmcnt(3)" ::: "memory");
    };

    // prologue: 3 tiles staged; drain tiles 0,1 (leave tile 2's LPT in flight)
    stage_all(0); stage_all(1); stage_all(2);
    wait_lpt();
    __builtin_amdgcn_s_barrier();
    asm volatile("" ::: "memory");

    for (int tt = 0; tt < NTtot; ++tt) {
        const unsigned short* slot = &lds[(tt & 3) * SLOT];
        const bool st = (tt + 3 < NTtot);
        v8s bf[4];
#pragma unroll
        for (int q = 0; q < NPH; ++q) {
            // ---- phase reads (consumed after the phase barrier)
            if (q == 0) {
#pragma unroll
                for (int ni = 0; ni < 4; ++ni) bf[ni] = rdB(slot, ni);
            }
            v8s a0 = rdA(slot, 2 * q);
            v8s a1 = rdA(slot, 2 * q + 1);
            // ---- spread next-tile staging across phases
            if (st) stage_part(tt + 3, q);
            // ---- phase barrier: lockstep wave roles (T3), then MFMA burst
            __builtin_amdgcn_s_barrier();
            asm volatile("" ::: "memory");
            __builtin_amdgcn_s_setprio(1);
#pragma unroll
            for (int ni = 0; ni < 4; ++ni) {
                if constexpr (DT == 0) {
                    acc[2 * q][ni]     = __builtin_amdgcn_mfma_f32_16x16x32_bf16(a0, bf[ni], acc[2 * q][ni], 0, 0, 0);
                    acc[2 * q + 1][ni] = __builtin_amdgcn_mfma_f32_16x16x32_bf16(a1, bf[ni], acc[2 * q + 1][ni], 0, 0, 0);
                } else {
                    acc[2 * q][ni]     = __builtin_amdgcn_mfma_f32_16x16x32_f16(as_h(a0), as_h(bf[ni]), acc[2 * q][ni], 0, 0, 0);
                    acc[2 * q + 1][ni] = __builtin_amdgcn_mfma_f32_16x16x32_f16(as_h(a1), as_h(bf[ni]), acc[2 * q + 1][ni], 0, 0, 0);
                }
            }
            __builtin_amdgcn_s_setprio(0);
        }
        // ---- iter boundary: counted drain (one tile early), barrier
        if (tt + 2 < NTtot) {
            if (tt + 3 < NTtot) wait_lpt();
            else                asm volatile("s_waitcnt vmcnt(0)" ::: "memory");
            __builtin_amdgcn_s_barrier();
            asm volatile("" ::: "memory");
        }
    }

    // ---- epilogue: bias/act folded into acc, f16 normal store
    const size_t crow0 = (size_t)zb * cZRows + m0;
#pragma unroll
    for (int ni = 0; ni < 4; ++ni) {
        int n = n0 + wn * 64 + ni * 16 + l15;
        float bv = (ACT > 0) ? bias[n] : 0.f;
        float av = (ACT == 2) ? alpha[n] : 0.f;
#pragma unroll
        for (int mi = 0; mi < MREP; ++mi) {
#pragma unroll
            for (int r = 0; r < 4; ++r) {
                int m = wm * (MREP * 16) + mi * 16 + quad * 4 + r;
                float v = acc[mi][ni][r] + bv;
                if (ACT == 1) v = v > 0.f ? v : 0.f;
                if (ACT == 2) v = v > 0.f ? v : av * v;
                acc[mi][ni][r] = v;
                o_[(crow0 + m) * (size_t)Nout + n] = f2h(v);
            }
        }
    }

    // ---- fused transposed bf16 store: HT[zbT][f][1024]
    if constexpr (WRT) {
        const int zbT = m0 >> 10;
        const int mloc0 = (m0 & 1023) + wm * (MREP * 16);
#pragma unroll
        for (int ni = 0; ni < 4; ++ni) {
            int f = n0 + wn * 64 + ni * 16 + l15;
            size_t rowb = (((size_t)zbT * Nout + f) << 10) + mloc0;
#pragma unroll
            for (int mi = 0; mi < MREP; ++mi) {
                ushort4 u;
                unsigned short* up = (unsigned short*)&u;
#pragma unroll
                for (int r = 0; r < 4; ++r) up[r] = f2bf(acc[mi][ni][r]);
                *(ushort4*)(th + rowb + mi * 16 + quad * 4) = u;
            }
        }
    }
}

// ---------------------------------------------------------------------------
// pred = H5 @ cW2 + cb2, H5 f16 single plane, fp32 accumulation
__global__ __launch_bounds__(256) void final_gemm(const unsigned short* __restrict__ hh,
                                                  const float* __restrict__ W,
                                                  const float* __restrict__ bias,
                                                  float* __restrict__ out) {
    const int t = threadIdx.x;
    const int m = blockIdx.x * 64 + (t >> 2);
    const int kq = (t & 3) * 64;
    const unsigned short* ph = hh + (size_t)m * 256 + kq;
    float a0 = 0.f, a1 = 0.f;
#pragma unroll
    for (int i = 0; i < 8; ++i) {
        uint4 vh = *(const uint4*)(ph + i * 8);
        const unsigned short* sh = (const unsigned short*)&vh;
#pragma unroll
        for (int j = 0; j < 8; ++j) {
            int k = kq + i * 8 + j;
            float h = h2f(sh[j]);
            a0 += h * W[k * 2];
            a1 += h * W[k * 2 + 1];
        }
    }
    a0 += __shfl_down(a0, 2); a0 += __shfl_down(a0, 1);
    a1 += __shfl_down(a1, 2); a1 += __shfl_down(a1, 1);
    if ((t & 3) == 0) {
        out[(size_t)m * 2] = a0 + bias[0];
        out[(size_t)m * 2 + 1] = a1 + bias[1];
    }
}

// ---------------------------------------------------------------------------
extern "C" void kernel_launch(void* const* d_in, const int* in_sizes, int n_in,
                              void* d_out, int out_size, void* d_ws, size_t ws_size,
                              hipStream_t stream) {
    const float* x   = (const float*)d_in[0];
    const float* adj = (const float*)d_in[1];
    const float* W1  = (const float*)d_in[2];
    const float* b1  = (const float*)d_in[3];
    const float* W2  = (const float*)d_in[4];
    const float* b2  = (const float*)d_in[5];
    const float* W3  = (const float*)d_in[6];
    const float* b3  = (const float*)d_in[7];
    const float* W4  = (const float*)d_in[8];
    const float* b4  = (const float*)d_in[9];
    const float* cW1 = (const float*)d_in[10];
    const float* cb1 = (const float*)d_in[11];
    const float* alp = (const float*)d_in[12];
    const float* cW2 = (const float*)d_in[13];
    const float* cb2 = (const float*)d_in[14];
    float* out = (float*)d_out;

    const size_t P   = 32768ull * 512;       // 16,777,216 ushorts per act plane
    const size_t XP  = 32768ull * 256;       // x f16 plane
    const size_t WT_TOT = 1245184;
    const size_t ADJ = 32ull * 1024 * 1024;

    unsigned short* N1  = (unsigned short*)d_ws;
    unsigned short* N2  = N1 + P;
    unsigned short* N3  = N2 + P;
    unsigned short* Th  = N3 + P;            // transposed activations, bf16
    unsigned short* X16 = Th + P;            // x as f16
    unsigned short* WT  = X16 + XP;          // transposed weights, f16
    unsigned short* SA  = WT + WT_TOT;       // adj bf16

    const size_t o1 = 0, o2 = 262144, o3 = 786432, o4 = 1048576, o5 = 1179648;
    const bool preAdj = ws_size >= (4 * P + XP + WT_TOT + ADJ) * sizeof(unsigned short);

    dim3 blk(256);
    dim3 blk5(512);

    tsplit16<<<dim3(8, 8),  blk, 0, stream>>>(W1,  WT + o1, 512, 512);
    tsplit16<<<dim3(16, 8), blk, 0, stream>>>(W2,  WT + o2, 1024, 512);
    tsplit16<<<dim3(16, 4), blk, 0, stream>>>(W3,  WT + o3, 1024, 256);
    tsplit16<<<dim3(8, 4),  blk, 0, stream>>>(W4,  WT + o4, 512, 256);
    tsplit16<<<dim3(4, 4),  blk, 0, stream>>>(cW1, WT + o5, 256, 256);
    if (preAdj)
        split_hi<<<32768, blk, 0, stream>>>(adj, SA, (int)(ADJ / 4));

    // x -> X16 (f16) + Th (bf16 transposed), single pass over x
    xprep<<<dim3(16, 4, 32), blk, 0, stream>>>(x, Th, X16, 256);

    // agg1 = adj @ x (N=256) -> N2
    if (preAdj)
        gemm256<0, false, 0, false, 128><<<256, blk5, 0, stream>>>(
            SA, nullptr, 1024, 0, Th, 1024, nullptr, nullptr,
            N2, 256, nullptr, (size_t)1 << 20, 256ull * 1024, 1024, 2, 2);
    else
        gemm128<0, false, 1, 0, false><<<512, blk, 0, stream>>>(
            adj, nullptr, 1024, 0, Th, 1024, nullptr, nullptr,
            N2, 256, nullptr, (size_t)1 << 20, 256ull * 1024, 1024, 2, 3);

    // dense1 = relu([x|AGG1] @ W1 + b1) (N=512) -> N3, fused H1T -> Th
    gemm256<1, true, 1, true, 256><<<256, blk5, 0, stream>>>(
        X16, N2, 256, 256, WT + o1, 512, b1, nullptr,
        N3, 512, Th, 0, 0, 0, 2, 7);

    // agg2 = adj @ H1 (N=512) -> N1
    if (preAdj)
        gemm256<0, false, 0, false, 256><<<256, blk5, 0, stream>>>(
            SA, nullptr, 1024, 0, Th, 1024, nullptr, nullptr,
            N1, 512, nullptr, (size_t)1 << 20, 512ull * 1024, 1024, 2, 2);
    else
        gemm128<0, false, 1, 0, false><<<1024, blk, 0, stream>>>(
            adj, nullptr, 1024, 0, Th, 1024, nullptr, nullptr,
            N1, 512, nullptr, (size_t)1 << 20, 512ull * 1024, 1024, 4, 3);

    // dense2 (N=512) -> N2, fused H2T -> Th
    gemm256<1, true, 1, true, 256><<<256, blk5, 0, stream>>>(
        N3, N1, 512, 512, WT + o2, 1024, b2, nullptr,
        N2, 512, Th, 0, 0, 0, 2, 7);

    // agg3 = adj @ H2 (N=512) -> N1
    if (preAdj)
        gemm256<0, false, 0, false, 256><<<256, blk5, 0, stream>>>(
            SA, nullptr, 1024, 0, Th, 1024, nullptr, nullptr,
            N1, 512, nullptr, (size_t)1 << 20, 512ull * 1024, 1024, 2, 2);
    else
        gemm128<0, false, 1, 0, false><<<1024, blk, 0, stream>>>(
            adj, nullptr, 1024, 0, Th, 1024, nullptr, nullptr,
            N1, 512, nullptr, (size_t)1 << 20, 512ull * 1024, 1024, 4, 3);

    // dense3 (N=256) -> N3, fused H3T -> Th
    gemm256<1, true, 1, true, 128><<<256, blk5, 0, stream>>>(
        N2, N1, 512, 512, WT + o3, 1024, b3, nullptr,
        N3, 256, Th, 0, 0, 0, 2, 7);

    // agg4 = adj @ H3 (N=256) -> N1
    if (preAdj)
        gemm256<0, false, 0, false, 128><<<256, blk5, 0, stream>>>(
            SA, nullptr, 1024, 0, Th, 1024, nullptr, nullptr,
            N1, 256, nullptr, (size_t)1 << 20, 256ull * 1024, 1024, 2, 2);
    else
        gemm128<0, false, 1, 0, false><<<512, blk, 0, stream>>>(
            adj, nullptr, 1024, 0, Th, 1024, nullptr, nullptr,
            N1, 256, nullptr, (size_t)1 << 20, 256ull * 1024, 1024, 2, 3);

    // dense4 (N=256) -> N2
    gemm256<1, true, 1, false, 128><<<256, blk5, 0, stream>>>(
        N3, N1, 256, 256, WT + o4, 512, b4, nullptr,
        N2, 256, nullptr, 0, 0, 0, 2, 7);

    // cls1 = prelu(H4 @ cW1 + cb1) (N=256) -> N3
    gemm256<2, false, 1, false, 128><<<256, blk5, 0, stream>>>(
        N2, nullptr, 256, 0, WT + o5, 256, cb1, alp,
        N3, 256, nullptr, 0, 0, 0, 2, 7);

    // final
    final_gemm<<<512, blk, 0, stream>>>(N3, cW2, cb2, out);
}

// Round 5
// 540.089 us; speedup vs baseline: 1.0259x; 1.0259x over previous
//
#include <hip/hip_runtime.h>

typedef short v8s __attribute__((ext_vector_type(8)));
typedef _Float16 v8h __attribute__((ext_vector_type(8)));
typedef float v4f __attribute__((ext_vector_type(4)));

#define BMT 128
#define BNT 128
#define BKT 32

__device__ __forceinline__ unsigned short f2bf(float f) {
    unsigned int u = __float_as_uint(f);
    u += 0x7fff + ((u >> 16) & 1);   // RNE
    return (unsigned short)(u >> 16);
}
__device__ __forceinline__ unsigned short f2h(float f) {
    union { _Float16 h; unsigned short u; } c;
    c.h = (_Float16)f;
    return c.u;
}
__device__ __forceinline__ float h2f(unsigned short v) {
    union { unsigned short u; _Float16 h; } c;
    c.u = v;
    return (float)c.h;
}
__device__ __forceinline__ v8h as_h(v8s x) {
    union { v8s s; v8h h; } c;
    c.s = x;
    return c.h;
}

union U128 { unsigned short s[8]; uint4 v; };

// async 16B global -> LDS (wave-uniform LDS base + lane*16 implicit)
__device__ __forceinline__ void gld16(const unsigned short* g, unsigned short* l) {
    __builtin_amdgcn_global_load_lds((const __attribute__((address_space(1))) void*)g,
                                     (__attribute__((address_space(3))) void*)l, 16, 0, 0);
}

// ---------------------------------------------------------------------------
// fp32 -> bf16 plane (adj)
__global__ __launch_bounds__(256) void split_hi(const float* __restrict__ x,
                                                unsigned short* __restrict__ oh, int n4) {
    int i = blockIdx.x * 256 + threadIdx.x;
    if (i < n4) {
        float4 f = ((const float4*)x)[i];
        float fv[4] = {f.x, f.y, f.z, f.w};
        ushort4 h;
        unsigned short* hp = (unsigned short*)&h;
#pragma unroll
        for (int j = 0; j < 4; ++j) hp[j] = f2bf(fv[j]);
        ((ushort4*)oh)[i] = h;
    }
}

// transpose-convert: W fp32 [R][C] -> WT f16 [C][R], 64x64 LDS tiles.
__global__ __launch_bounds__(256) void tsplit16(const float* __restrict__ W,
                                                unsigned short* __restrict__ th, int R, int C) {
    __shared__ unsigned short lds[64][80];   // [c][r], padded
    const int t = threadIdx.x;
    const int rt = blockIdx.x, ct = blockIdx.y;
    const int r = t >> 2, c0 = (t & 3) * 16;
    const float* src = W + (size_t)(rt * 64 + r) * C + ct * 64 + c0;
#pragma unroll
    for (int j = 0; j < 16; j += 4) {
        float4 f = *(const float4*)(src + j);
        lds[c0 + j + 0][r] = f2h(f.x);
        lds[c0 + j + 1][r] = f2h(f.y);
        lds[c0 + j + 2][r] = f2h(f.z);
        lds[c0 + j + 3][r] = f2h(f.w);
    }
    __syncthreads();
    const int c = t >> 2, r0 = (t & 3) * 16;
    U128 u0, u1;
#pragma unroll
    for (int j = 0; j < 8; ++j) { u0.s[j] = lds[c][r0 + j]; u1.s[j] = lds[c][r0 + 8 + j]; }
    unsigned short* dst = th + (size_t)(ct * 64 + c) * R + rt * 64 + r0;
    *(uint4*)dst = u0.v;
    *(uint4*)(dst + 8) = u1.v;
}

// ---------------------------------------------------------------------------
// Fused x preprocessing (reads x fp32 ONCE):
//   X16 f16 [z*1024+node][256]  (dense1 A operand)
//   Th  bf16 [z*256+f][1024]    (agg1 B operand, transposed)
__global__ __launch_bounds__(256) void xprep(const float* __restrict__ src,
                                             unsigned short* __restrict__ th,
                                             unsigned short* __restrict__ x16, int d) {
    __shared__ unsigned int lds[64 * 66];
    const int t = threadIdx.x;
    const int mt = blockIdx.x, ft = blockIdx.y, z = blockIdx.z;
    const int r = t >> 3, c8 = (t & 7) * 8;
#pragma unroll
    for (int half = 0; half < 2; ++half) {
        int rr = r + half * 32;
        size_t grow = (size_t)z * 1024 + mt * 64 + rr;
        const float* xs = src + grow * d + ft * 64 + c8;
        float4 f0 = *(const float4*)xs;
        float4 f1 = *(const float4*)(xs + 4);
        float fv[8] = {f0.x, f0.y, f0.z, f0.w, f1.x, f1.y, f1.z, f1.w};
        U128 uh;
#pragma unroll
        for (int j = 0; j < 8; ++j) {
            lds[rr * 66 + c8 + j] = f2bf(fv[j]);
            uh.s[j] = f2h(fv[j]);
        }
        *(uint4*)(x16 + grow * d + ft * 64 + c8) = uh.v;
    }
    __syncthreads();
    const int f = t >> 3, m0 = (t & 7) * 8;
#pragma unroll
    for (int half = 0; half < 2; ++half) {
        int ff = f + half * 32;
        U128 uh;
#pragma unroll
        for (int j = 0; j < 8; ++j)
            uh.s[j] = (unsigned short)lds[(m0 + j) * 66 + ff];
        size_t orow = ((size_t)z * d + ft * 64 + ff) * 1024 + mt * 64 + m0;
        *(uint4*)(th + orow) = uh.v;
    }
}

// ---------------------------------------------------------------------------
// Legacy 128x128x32 GEMM (m97-structure) — kept only for the fp32-adj fallback.
template <int ACT, bool TWO, int AMODE, int DT, bool WRT>
__global__ __launch_bounds__(256) void gemm128(
    const void* a1, const unsigned short* __restrict__ a2,
    int K1, int K2,
    const unsigned short* __restrict__ b_, int ldb,
    const float* __restrict__ bias, const float* __restrict__ alpha,
    unsigned short* __restrict__ o_, int Nout,
    unsigned short* __restrict__ th,
    size_t aZ, size_t bZ, int cZRows,
    int nblk, int mBits)
{
    constexpr int LA = (AMODE == 0) ? 32 : 40;
    constexpr int LB = 32;
    __shared__ __align__(16) unsigned short Ash[BMT * LA];
    __shared__ __align__(16) unsigned short Bsh[BNT * LB];

    const int t = threadIdx.x;
    const int lane = t & 63, wave = t >> 6;
    const int wm = wave >> 1, wn = wave & 1;
    const int l15 = lane & 15, quad = lane >> 4;

    const int bx = blockIdx.x;
    const int low3 = bx & 7, rest = bx >> 3;
    const int nIdx = rest % nblk, g = rest / nblk;
    const int grp = g * 8 + low3;
    const int m0 = (grp & ((1 << mBits) - 1)) * BMT;
    const int zb = grp >> mBits;
    const int n0 = nIdx * BNT;

    const unsigned short* bhz = b_ + (size_t)zb * bZ;

    v4f acc[4][4] = {};

    const int nch = TWO ? 2 : 1;
    for (int ch = 0; ch < nch; ++ch) {
        const int K = (TWO && ch) ? K2 : K1;
        const int kr0 = (TWO && ch) ? K1 : 0;
        const unsigned short* ah = nullptr;
        const float* af = nullptr;
        if constexpr (AMODE == 0)
            ah = (ch ? a2 : (const unsigned short*)a1) + (size_t)zb * aZ;
        else
            af = (const float*)a1 + (size_t)zb * aZ;

        for (int kk = 0; kk < K; kk += BKT) {
            __syncthreads();
            if constexpr (AMODE == 0) {
#pragma unroll
                for (int i = 0; i < 2; ++i) {
                    int s = i * 256 + t;
                    int row = s >> 2;
                    int cg = (s & 3) ^ ((s >> 3) & 3);
                    size_t go = (size_t)(m0 + row) * K + kk + cg * 8;
                    int ls = (i * 256 + (t & ~63)) * 8;
                    gld16(ah + go, &Ash[ls]);
                }
            } else {
#pragma unroll
                for (int i = 0; i < 2; ++i) {
                    int cid = i * 256 + t;
                    int row = cid >> 2, c = cid & 3;
                    const float* src = af + (size_t)(m0 + row) * K + kk + c * 8;
                    float4 f0 = *(const float4*)src;
                    float4 f1 = *(const float4*)(src + 4);
                    float fv[8] = {f0.x, f0.y, f0.z, f0.w, f1.x, f1.y, f1.z, f1.w};
                    U128 uh;
#pragma unroll
                    for (int j = 0; j < 8; ++j) uh.s[j] = f2bf(fv[j]);
                    *(uint4*)&Ash[row * LA + c * 8] = uh.v;
                }
            }
#pragma unroll
            for (int i = 0; i < 2; ++i) {
                int s = i * 256 + t;
                int row = s >> 2;
                int cg = (s & 3) ^ ((s >> 3) & 3);
                size_t go = (size_t)(n0 + row) * ldb + kr0 + kk + cg * 8;
                int ls = (i * 256 + (t & ~63)) * 8;
                gld16(bhz + go, &Bsh[ls]);
            }
            __syncthreads();
            v8s ahf[4];
#pragma unroll
            for (int mi = 0; mi < 4; ++mi) {
                int row = wm * 64 + mi * 16 + l15;
                int off;
                if constexpr (AMODE == 0) off = row * LA + ((quad ^ ((row >> 1) & 3)) * 8);
                else                      off = row * LA + quad * 8;
                ahf[mi] = *(const v8s*)&Ash[off];
            }
#pragma unroll
            for (int ni = 0; ni < 4; ++ni) {
                int row = wn * 64 + ni * 16 + l15;
                int off = row * LB + ((quad ^ ((row >> 1) & 3)) * 8);
                v8s bhf = *(const v8s*)&Bsh[off];
#pragma unroll
                for (int mi = 0; mi < 4; ++mi) {
                    if constexpr (DT == 0)
                        acc[mi][ni] = __builtin_amdgcn_mfma_f32_16x16x32_bf16(ahf[mi], bhf, acc[mi][ni], 0, 0, 0);
                    else
                        acc[mi][ni] = __builtin_amdgcn_mfma_f32_16x16x32_f16(as_h(ahf[mi]), as_h(bhf), acc[mi][ni], 0, 0, 0);
                }
            }
        }
    }

    const size_t crow0 = (size_t)zb * cZRows + m0;
#pragma unroll
    for (int ni = 0; ni < 4; ++ni) {
        int n = n0 + wn * 64 + ni * 16 + l15;
        float bv = (ACT > 0) ? bias[n] : 0.f;
        float av = (ACT == 2) ? alpha[n] : 0.f;
#pragma unroll
        for (int mi = 0; mi < 4; ++mi) {
#pragma unroll
            for (int r = 0; r < 4; ++r) {
                int m = wm * 64 + mi * 16 + quad * 4 + r;
                float v = acc[mi][ni][r] + bv;
                if (ACT == 1) v = v > 0.f ? v : 0.f;
                if (ACT == 2) v = v > 0.f ? v : av * v;
                acc[mi][ni][r] = v;
                o_[(crow0 + m) * (size_t)Nout + n] = f2h(v);
            }
        }
    }

    if constexpr (WRT) {
        const int zbT = m0 >> 10;
        const int mloc0 = (m0 & 1023) + wm * 64;
#pragma unroll
        for (int ni = 0; ni < 4; ++ni) {
            int f = n0 + wn * 64 + ni * 16 + l15;
            size_t rowb = (((size_t)zbT * Nout + f) << 10) + mloc0;
#pragma unroll
            for (int mi = 0; mi < 4; ++mi) {
                ushort4 u;
                unsigned short* up = (unsigned short*)&u;
#pragma unroll
                for (int r = 0; r < 4; ++r) up[r] = f2bf(acc[mi][ni][r]);
                *(ushort4*)(th + rowb + mi * 16 + quad * 4) = u;
            }
        }
    }
}

// ---------------------------------------------------------------------------
// 256-wide phase-interleaved GEMM (T-stack over ring-4 skeleton) with
// XCD-locality chunked block decode.
//   Grid is ALWAYS 256 (1 block/CU, all blocks co-resident) and nblk==2.
//   Z32=true  (batched aggs, zcnt=32, mcnt=4): per XCD: 4 zb x 4 m x 2 n
//     -> B panel fetched into ONE L2 (was 4), A panel into one (was 2).
//   Z32=false (denses, mcnt=128): per XCD: 16 m x 2 n, nIdx pair adjacent
//     -> A panel fetched once (was 2); weights L2/LLC-resident.
// Race-freedom (unchanged): stage(t+3) writes slot (t-1)&3 whose reads
// drained before the previous iter barrier. vmcnt oldest-first: with
// {t+2,t+3} in flight (2*LPT), vmcnt(LPT) <=> t+2 fully landed.
template <int ACT, bool TWO, int DT, bool WRT, int BN2, bool Z32>
__global__ __launch_bounds__(512, 2) void gemm256(
    const unsigned short* __restrict__ a1, const unsigned short* __restrict__ a2,
    int K1, int K2,
    const unsigned short* __restrict__ b_, int ldb,
    const float* __restrict__ bias, const float* __restrict__ alpha,
    unsigned short* __restrict__ o_, int Nout,
    unsigned short* __restrict__ th,
    size_t aZ, size_t bZ, int cZRows)
{
    constexpr int ASLOT = 256 * 32;          // ushorts per A K-tile
    constexpr int BSLOT = BN2 * 32;
    constexpr int SLOT  = ASLOT + BSLOT;
    constexpr int LPT   = 2 + BN2 / 128;     // gld16 per thread per K-tile (4 or 3)
    constexpr int WN    = BN2 / 64;          // waves along N (4 or 2)
    constexpr int WM    = 8 / WN;            // waves along M (2 or 4)
    constexpr int MREP  = 16 / WM;           // 16x16 frags along M per wave (8 or 4)
    constexpr int NPH   = MREP / 2;          // phases per K-tile (4 or 2)
    __shared__ __align__(16) unsigned short lds[4 * SLOT];

    const int t = threadIdx.x;
    const int lane = t & 63, wave = t >> 6;
    const int wm = wave / WN, wn = wave % WN;
    const int l15 = lane & 15, quad = lane >> 4;

    // XCD-locality chunked decode (bijective; grid == 256, nblk == 2)
    const int bx = blockIdx.x;
    const int xcd = bx & 7, loc = bx >> 3;   // loc 0..31
    int zb, mIdx, nIdx;
    if constexpr (Z32) {
        zb = xcd * 4 + (loc >> 3);           // 4 zb per XCD
        mIdx = (loc >> 1) & 3;               // 4 m-tiles
        nIdx = loc & 1;                      // n-pair adjacent
    } else {
        zb = 0;
        mIdx = xcd * 16 + (loc >> 1);        // 16 m-tiles per XCD
        nIdx = loc & 1;                      // n-pair adjacent (A-panel shared)
    }
    const int m0 = mIdx * 256;
    const int n0 = nIdx * BN2;

    const unsigned short* A1 = a1 + (size_t)zb * aZ;
    const unsigned short* A2p = TWO ? (a2 + (size_t)zb * aZ) : nullptr;
    const unsigned short* B = b_ + (size_t)zb * bZ;

    const int NT1 = K1 >> 5;
    const int NTtot = NT1 + (TWO ? (K2 >> 5) : 0);   // >= 8

    // issue part p (0..NPH-1) of tile tt's staging
    auto stage_part = [&](int tt, int p) {
        unsigned short* slot = &lds[(tt & 3) * SLOT];
        const unsigned short* abase;
        int astr;
        if constexpr (TWO) {
            if (tt >= NT1) { abase = A2p + ((size_t)(tt - NT1) << 5); astr = K2; }
            else           { abase = A1 + ((size_t)tt << 5); astr = K1; }
        } else {
            abase = A1 + ((size_t)tt << 5); astr = K1;
        }
        auto lda = [&](int i) {
            int s = i * 512 + t;
            int row = s >> 2;
            int cg = (s & 3) ^ ((s >> 3) & 3);            // read-side-matched swizzle
            gld16(abase + (size_t)(m0 + row) * astr + cg * 8,
                  &slot[(i * 512 + (t & ~63)) * 8]);
        };
        auto ldb_ = [&](int i) {
            const unsigned short* bbase = B + ((size_t)tt << 5);
            int s = i * 512 + t;
            int row = s >> 2;
            int cg = (s & 3) ^ ((s >> 3) & 3);
            gld16(bbase + (size_t)(n0 + row) * ldb + cg * 8,
                  &slot[ASLOT + (i * 512 + (t & ~63)) * 8]);
        };
        if constexpr (BN2 == 256) {
            if (p < 2) lda(p); else ldb_(p - 2);
        } else {
            if (p == 0) { lda(0); lda(1); } else ldb_(0);
        }
    };
    auto stage_all = [&](int tt) {
#pragma unroll
        for (int p = 0; p < NPH; ++p) stage_part(tt, p);
    };

    v4f acc[MREP][4] = {};

    auto rdA = [&](const unsigned short* slot, int mi) -> v8s {
        int row = wm * (MREP * 16) + mi * 16 + l15;
        return *(const v8s*)&slot[row * 32 + ((quad ^ ((row >> 1) & 3)) * 8)];
    };
    auto rdB = [&](const unsigned short* slot, int ni) -> v8s {
        int row = wn * 64 + ni * 16 + l15;
        return *(const v8s*)&slot[ASLOT + row * 32 + ((quad ^ ((row >> 1) & 3)) * 8)];
    };

    auto wait_lpt = [&]() {
        if constexpr (LPT == 4) asm volatile("s_waitcnt vmcnt(4)" ::: "memory");
        else                    asm volatile("s_waitcnt vmcnt(3)" ::: "memory");
    };

    // prologue: 3 tiles staged; drain tiles 0,1 (leave tile 2's LPT in flight)
    stage_all(0); stage_all(1); stage_all(2);
    wait_lpt();
    __builtin_amdgcn_s_barrier();
    asm volatile("" ::: "memory");

    for (int tt = 0; tt < NTtot; ++tt) {
        const unsigned short* slot = &lds[(tt & 3) * SLOT];
        const bool st = (tt + 3 < NTtot);
        v8s bf[4];
#pragma unroll
        for (int q = 0; q < NPH; ++q) {
            if (q == 0) {
#pragma unroll
                for (int ni = 0; ni < 4; ++ni) bf[ni] = rdB(slot, ni);
            }
            v8s a0 = rdA(slot, 2 * q);
            v8s a1 = rdA(slot, 2 * q + 1);
            if (st) stage_part(tt + 3, q);
            __builtin_amdgcn_s_barrier();
            asm volatile("" ::: "memory");
            __builtin_amdgcn_s_setprio(1);
#pragma unroll
            for (int ni = 0; ni < 4; ++ni) {
                if constexpr (DT == 0) {
                    acc[2 * q][ni]     = __builtin_amdgcn_mfma_f32_16x16x32_bf16(a0, bf[ni], acc[2 * q][ni], 0, 0, 0);
                    acc[2 * q + 1][ni] = __builtin_amdgcn_mfma_f32_16x16x32_bf16(a1, bf[ni], acc[2 * q + 1][ni], 0, 0, 0);
                } else {
                    acc[2 * q][ni]     = __builtin_amdgcn_mfma_f32_16x16x32_f16(as_h(a0), as_h(bf[ni]), acc[2 * q][ni], 0, 0, 0);
                    acc[2 * q + 1][ni] = __builtin_amdgcn_mfma_f32_16x16x32_f16(as_h(a1), as_h(bf[ni]), acc[2 * q + 1][ni], 0, 0, 0);
                }
            }
            __builtin_amdgcn_s_setprio(0);
        }
        if (tt + 2 < NTtot) {
            if (tt + 3 < NTtot) wait_lpt();
            else                asm volatile("s_waitcnt vmcnt(0)" ::: "memory");
            __builtin_amdgcn_s_barrier();
            asm volatile("" ::: "memory");
        }
    }

    // ---- epilogue: bias/act folded into acc, f16 normal store
    const size_t crow0 = (size_t)zb * cZRows + m0;
#pragma unroll
    for (int ni = 0; ni < 4; ++ni) {
        int n = n0 + wn * 64 + ni * 16 + l15;
        float bv = (ACT > 0) ? bias[n] : 0.f;
        float av = (ACT == 2) ? alpha[n] : 0.f;
#pragma unroll
        for (int mi = 0; mi < MREP; ++mi) {
#pragma unroll
            for (int r = 0; r < 4; ++r) {
                int m = wm * (MREP * 16) + mi * 16 + quad * 4 + r;
                float v = acc[mi][ni][r] + bv;
                if (ACT == 1) v = v > 0.f ? v : 0.f;
                if (ACT == 2) v = v > 0.f ? v : av * v;
                acc[mi][ni][r] = v;
                o_[(crow0 + m) * (size_t)Nout + n] = f2h(v);
            }
        }
    }

    // ---- fused transposed bf16 store: HT[zbT][f][1024]
    if constexpr (WRT) {
        const int zbT = m0 >> 10;
        const int mloc0 = (m0 & 1023) + wm * (MREP * 16);
#pragma unroll
        for (int ni = 0; ni < 4; ++ni) {
            int f = n0 + wn * 64 + ni * 16 + l15;
            size_t rowb = (((size_t)zbT * Nout + f) << 10) + mloc0;
#pragma unroll
            for (int mi = 0; mi < MREP; ++mi) {
                ushort4 u;
                unsigned short* up = (unsigned short*)&u;
#pragma unroll
                for (int r = 0; r < 4; ++r) up[r] = f2bf(acc[mi][ni][r]);
                *(ushort4*)(th + rowb + mi * 16 + quad * 4) = u;
            }
        }
    }
}

// ---------------------------------------------------------------------------
// pred = H5 @ cW2 + cb2, H5 f16 single plane, fp32 accumulation
__global__ __launch_bounds__(256) void final_gemm(const unsigned short* __restrict__ hh,
                                                  const float* __restrict__ W,
                                                  const float* __restrict__ bias,
                                                  float* __restrict__ out) {
    const int t = threadIdx.x;
    const int m = blockIdx.x * 64 + (t >> 2);
    const int kq = (t & 3) * 64;
    const unsigned short* ph = hh + (size_t)m * 256 + kq;
    float a0 = 0.f, a1 = 0.f;
#pragma unroll
    for (int i = 0; i < 8; ++i) {
        uint4 vh = *(const uint4*)(ph + i * 8);
        const unsigned short* sh = (const unsigned short*)&vh;
#pragma unroll
        for (int j = 0; j < 8; ++j) {
            int k = kq + i * 8 + j;
            float h = h2f(sh[j]);
            a0 += h * W[k * 2];
            a1 += h * W[k * 2 + 1];
        }
    }
    a0 += __shfl_down(a0, 2); a0 += __shfl_down(a0, 1);
    a1 += __shfl_down(a1, 2); a1 += __shfl_down(a1, 1);
    if ((t & 3) == 0) {
        out[(size_t)m * 2] = a0 + bias[0];
        out[(size_t)m * 2 + 1] = a1 + bias[1];
    }
}

// ---------------------------------------------------------------------------
extern "C" void kernel_launch(void* const* d_in, const int* in_sizes, int n_in,
                              void* d_out, int out_size, void* d_ws, size_t ws_size,
                              hipStream_t stream) {
    const float* x   = (const float*)d_in[0];
    const float* adj = (const float*)d_in[1];
    const float* W1  = (const float*)d_in[2];
    const float* b1  = (const float*)d_in[3];
    const float* W2  = (const float*)d_in[4];
    const float* b2  = (const float*)d_in[5];
    const float* W3  = (const float*)d_in[6];
    const float* b3  = (const float*)d_in[7];
    const float* W4  = (const float*)d_in[8];
    const float* b4  = (const float*)d_in[9];
    const float* cW1 = (const float*)d_in[10];
    const float* cb1 = (const float*)d_in[11];
    const float* alp = (const float*)d_in[12];
    const float* cW2 = (const float*)d_in[13];
    const float* cb2 = (const float*)d_in[14];
    float* out = (float*)d_out;

    const size_t P   = 32768ull * 512;       // 16,777,216 ushorts per act plane
    const size_t XP  = 32768ull * 256;       // x f16 plane
    const size_t WT_TOT = 1245184;
    const size_t ADJ = 32ull * 1024 * 1024;

    unsigned short* N1  = (unsigned short*)d_ws;
    unsigned short* N2  = N1 + P;
    unsigned short* N3  = N2 + P;
    unsigned short* Th  = N3 + P;            // transposed activations, bf16
    unsigned short* X16 = Th + P;            // x as f16
    unsigned short* WT  = X16 + XP;          // transposed weights, f16
    unsigned short* SA  = WT + WT_TOT;       // adj bf16

    const size_t o1 = 0, o2 = 262144, o3 = 786432, o4 = 1048576, o5 = 1179648;
    const bool preAdj = ws_size >= (4 * P + XP + WT_TOT + ADJ) * sizeof(unsigned short);

    dim3 blk(256);
    dim3 blk5(512);

    tsplit16<<<dim3(8, 8),  blk, 0, stream>>>(W1,  WT + o1, 512, 512);
    tsplit16<<<dim3(16, 8), blk, 0, stream>>>(W2,  WT + o2, 1024, 512);
    tsplit16<<<dim3(16, 4), blk, 0, stream>>>(W3,  WT + o3, 1024, 256);
    tsplit16<<<dim3(8, 4),  blk, 0, stream>>>(W4,  WT + o4, 512, 256);
    tsplit16<<<dim3(4, 4),  blk, 0, stream>>>(cW1, WT + o5, 256, 256);
    if (preAdj)
        split_hi<<<32768, blk, 0, stream>>>(adj, SA, (int)(ADJ / 4));

    // x -> X16 (f16) + Th (bf16 transposed), single pass over x
    xprep<<<dim3(16, 4, 32), blk, 0, stream>>>(x, Th, X16, 256);

    // agg1 = adj @ x (N=256) -> N2
    if (preAdj)
        gemm256<0, false, 0, false, 128, true><<<256, blk5, 0, stream>>>(
            SA, nullptr, 1024, 0, Th, 1024, nullptr, nullptr,
            N2, 256, nullptr, (size_t)1 << 20, 256ull * 1024, 1024);
    else
        gemm128<0, false, 1, 0, false><<<512, blk, 0, stream>>>(
            adj, nullptr, 1024, 0, Th, 1024, nullptr, nullptr,
            N2, 256, nullptr, (size_t)1 << 20, 256ull * 1024, 1024, 2, 3);

    // dense1 = relu([x|AGG1] @ W1 + b1) (N=512) -> N3, fused H1T -> Th
    gemm256<1, true, 1, true, 256, false><<<256, blk5, 0, stream>>>(
        X16, N2, 256, 256, WT + o1, 512, b1, nullptr,
        N3, 512, Th, 0, 0, 0);

    // agg2 = adj @ H1 (N=512) -> N1
    if (preAdj)
        gemm256<0, false, 0, false, 256, true><<<256, blk5, 0, stream>>>(
            SA, nullptr, 1024, 0, Th, 1024, nullptr, nullptr,
            N1, 512, nullptr, (size_t)1 << 20, 512ull * 1024, 1024);
    else
        gemm128<0, false, 1, 0, false><<<1024, blk, 0, stream>>>(
            adj, nullptr, 1024, 0, Th, 1024, nullptr, nullptr,
            N1, 512, nullptr, (size_t)1 << 20, 512ull * 1024, 1024, 4, 3);

    // dense2 (N=512) -> N2, fused H2T -> Th
    gemm256<1, true, 1, true, 256, false><<<256, blk5, 0, stream>>>(
        N3, N1, 512, 512, WT + o2, 1024, b2, nullptr,
        N2, 512, Th, 0, 0, 0);

    // agg3 = adj @ H2 (N=512) -> N1
    if (preAdj)
        gemm256<0, false, 0, false, 256, true><<<256, blk5, 0, stream>>>(
            SA, nullptr, 1024, 0, Th, 1024, nullptr, nullptr,
            N1, 512, nullptr, (size_t)1 << 20, 512ull * 1024, 1024);
    else
        gemm128<0, false, 1, 0, false><<<1024, blk, 0, stream>>>(
            adj, nullptr, 1024, 0, Th, 1024, nullptr, nullptr,
            N1, 512, nullptr, (size_t)1 << 20, 512ull * 1024, 1024, 4, 3);

    // dense3 (N=256) -> N3, fused H3T -> Th
    gemm256<1, true, 1, true, 128, false><<<256, blk5, 0, stream>>>(
        N2, N1, 512, 512, WT + o3, 1024, b3, nullptr,
        N3, 256, Th, 0, 0, 0);

    // agg4 = adj @ H3 (N=256) -> N1
    if (preAdj)
        gemm256<0, false, 0, false, 128, true><<<256, blk5, 0, stream>>>(
            SA, nullptr, 1024, 0, Th, 1024, nullptr, nullptr,
            N1, 256, nullptr, (size_t)1 << 20, 256ull * 1024, 1024);
    else
        gemm128<0, false, 1, 0, false><<<512, blk, 0, stream>>>(
            adj, nullptr, 1024, 0, Th, 1024, nullptr, nullptr,
            N1, 256, nullptr, (size_t)1 << 20, 256ull * 1024, 1024, 2, 3);

    // dense4 (N=256) -> N2
    gemm256<1, true, 1, false, 128, false><<<256, blk5, 0, stream>>>(
        N3, N1, 256, 256, WT + o4, 512, b4, nullptr,
        N2, 256, nullptr, 0, 0, 0);

    // cls1 = prelu(H4 @ cW1 + cb1) (N=256) -> N3
    gemm256<2, false, 1, false, 128, false><<<256, blk5, 0, stream>>>(
        N2, nullptr, 256, 0, WT + o5, 256, cb1, alp,
        N3, 256, nullptr, 0, 0, 0);

    // final
    final_gemm<<<512, blk, 0, stream>>>(N3, cW2, cb2, out);
}

// Round 6
// 530.519 us; speedup vs baseline: 1.0444x; 1.0180x over previous
//
#include <hip/hip_runtime.h>

typedef short v8s __attribute__((ext_vector_type(8)));
typedef _Float16 v8h __attribute__((ext_vector_type(8)));
typedef float v4f __attribute__((ext_vector_type(4)));

#define BMT 128
#define BNT 128
#define BKT 32

__device__ __forceinline__ unsigned short f2bf(float f) {
    unsigned int u = __float_as_uint(f);
    u += 0x7fff + ((u >> 16) & 1);   // RNE
    return (unsigned short)(u >> 16);
}
__device__ __forceinline__ unsigned short f2h(float f) {
    union { _Float16 h; unsigned short u; } c;
    c.h = (_Float16)f;
    return c.u;
}
__device__ __forceinline__ float h2f(unsigned short v) {
    union { unsigned short u; _Float16 h; } c;
    c.u = v;
    return (float)c.h;
}
__device__ __forceinline__ v8h as_h(v8s x) {
    union { v8s s; v8h h; } c;
    c.s = x;
    return c.h;
}

union U128 { unsigned short s[8]; uint4 v; };

// async 16B global -> LDS (wave-uniform LDS base + lane*16 implicit)
__device__ __forceinline__ void gld16(const unsigned short* g, unsigned short* l) {
    __builtin_amdgcn_global_load_lds((const __attribute__((address_space(1))) void*)g,
                                     (__attribute__((address_space(3))) void*)l, 16, 0, 0);
}

// ---------------------------------------------------------------------------
// fp32 -> bf16 plane (adj)
__global__ __launch_bounds__(256) void split_hi(const float* __restrict__ x,
                                                unsigned short* __restrict__ oh, int n4) {
    int i = blockIdx.x * 256 + threadIdx.x;
    if (i < n4) {
        float4 f = ((const float4*)x)[i];
        float fv[4] = {f.x, f.y, f.z, f.w};
        ushort4 h;
        unsigned short* hp = (unsigned short*)&h;
#pragma unroll
        for (int j = 0; j < 4; ++j) hp[j] = f2bf(fv[j]);
        ((ushort4*)oh)[i] = h;
    }
}

// transpose-convert: W fp32 [R][C] -> WT f16 [C][R], 64x64 LDS tiles.
__global__ __launch_bounds__(256) void tsplit16(const float* __restrict__ W,
                                                unsigned short* __restrict__ th, int R, int C) {
    __shared__ unsigned short lds[64][80];   // [c][r], padded
    const int t = threadIdx.x;
    const int rt = blockIdx.x, ct = blockIdx.y;
    const int r = t >> 2, c0 = (t & 3) * 16;
    const float* src = W + (size_t)(rt * 64 + r) * C + ct * 64 + c0;
#pragma unroll
    for (int j = 0; j < 16; j += 4) {
        float4 f = *(const float4*)(src + j);
        lds[c0 + j + 0][r] = f2h(f.x);
        lds[c0 + j + 1][r] = f2h(f.y);
        lds[c0 + j + 2][r] = f2h(f.z);
        lds[c0 + j + 3][r] = f2h(f.w);
    }
    __syncthreads();
    const int c = t >> 2, r0 = (t & 3) * 16;
    U128 u0, u1;
#pragma unroll
    for (int j = 0; j < 8; ++j) { u0.s[j] = lds[c][r0 + j]; u1.s[j] = lds[c][r0 + 8 + j]; }
    unsigned short* dst = th + (size_t)(ct * 64 + c) * R + rt * 64 + r0;
    *(uint4*)dst = u0.v;
    *(uint4*)(dst + 8) = u1.v;
}

// ---------------------------------------------------------------------------
// Fused x preprocessing (reads x fp32 ONCE):
//   X16 f16 [z*1024+node][256]  (dense1 A operand)
//   Th  bf16 [z*256+f][1024]    (agg1 B operand, transposed)
__global__ __launch_bounds__(256) void xprep(const float* __restrict__ src,
                                             unsigned short* __restrict__ th,
                                             unsigned short* __restrict__ x16, int d) {
    __shared__ unsigned int lds[64 * 66];
    const int t = threadIdx.x;
    const int mt = blockIdx.x, ft = blockIdx.y, z = blockIdx.z;
    const int r = t >> 3, c8 = (t & 7) * 8;
#pragma unroll
    for (int half = 0; half < 2; ++half) {
        int rr = r + half * 32;
        size_t grow = (size_t)z * 1024 + mt * 64 + rr;
        const float* xs = src + grow * d + ft * 64 + c8;
        float4 f0 = *(const float4*)xs;
        float4 f1 = *(const float4*)(xs + 4);
        float fv[8] = {f0.x, f0.y, f0.z, f0.w, f1.x, f1.y, f1.z, f1.w};
        U128 uh;
#pragma unroll
        for (int j = 0; j < 8; ++j) {
            lds[rr * 66 + c8 + j] = f2bf(fv[j]);
            uh.s[j] = f2h(fv[j]);
        }
        *(uint4*)(x16 + grow * d + ft * 64 + c8) = uh.v;
    }
    __syncthreads();
    const int f = t >> 3, m0 = (t & 7) * 8;
#pragma unroll
    for (int half = 0; half < 2; ++half) {
        int ff = f + half * 32;
        U128 uh;
#pragma unroll
        for (int j = 0; j < 8; ++j)
            uh.s[j] = (unsigned short)lds[(m0 + j) * 66 + ff];
        size_t orow = ((size_t)z * d + ft * 64 + ff) * 1024 + mt * 64 + m0;
        *(uint4*)(th + orow) = uh.v;
    }
}

// ---------------------------------------------------------------------------
// Legacy 128x128x32 GEMM (m97-structure) — kept only for the fp32-adj fallback.
template <int ACT, bool TWO, int AMODE, int DT, bool WRT>
__global__ __launch_bounds__(256) void gemm128(
    const void* a1, const unsigned short* __restrict__ a2,
    int K1, int K2,
    const unsigned short* __restrict__ b_, int ldb,
    const float* __restrict__ bias, const float* __restrict__ alpha,
    unsigned short* __restrict__ o_, int Nout,
    unsigned short* __restrict__ th,
    size_t aZ, size_t bZ, int cZRows,
    int nblk, int mBits)
{
    constexpr int LA = (AMODE == 0) ? 32 : 40;
    constexpr int LB = 32;
    __shared__ __align__(16) unsigned short Ash[BMT * LA];
    __shared__ __align__(16) unsigned short Bsh[BNT * LB];

    const int t = threadIdx.x;
    const int lane = t & 63, wave = t >> 6;
    const int wm = wave >> 1, wn = wave & 1;
    const int l15 = lane & 15, quad = lane >> 4;

    const int bx = blockIdx.x;
    const int low3 = bx & 7, rest = bx >> 3;
    const int nIdx = rest % nblk, g = rest / nblk;
    const int grp = g * 8 + low3;
    const int m0 = (grp & ((1 << mBits) - 1)) * BMT;
    const int zb = grp >> mBits;
    const int n0 = nIdx * BNT;

    const unsigned short* bhz = b_ + (size_t)zb * bZ;

    v4f acc[4][4] = {};

    const int nch = TWO ? 2 : 1;
    for (int ch = 0; ch < nch; ++ch) {
        const int K = (TWO && ch) ? K2 : K1;
        const int kr0 = (TWO && ch) ? K1 : 0;
        const unsigned short* ah = nullptr;
        const float* af = nullptr;
        if constexpr (AMODE == 0)
            ah = (ch ? a2 : (const unsigned short*)a1) + (size_t)zb * aZ;
        else
            af = (const float*)a1 + (size_t)zb * aZ;

        for (int kk = 0; kk < K; kk += BKT) {
            __syncthreads();
            if constexpr (AMODE == 0) {
#pragma unroll
                for (int i = 0; i < 2; ++i) {
                    int s = i * 256 + t;
                    int row = s >> 2;
                    int cg = (s & 3) ^ ((s >> 3) & 3);
                    size_t go = (size_t)(m0 + row) * K + kk + cg * 8;
                    int ls = (i * 256 + (t & ~63)) * 8;
                    gld16(ah + go, &Ash[ls]);
                }
            } else {
#pragma unroll
                for (int i = 0; i < 2; ++i) {
                    int cid = i * 256 + t;
                    int row = cid >> 2, c = cid & 3;
                    const float* src = af + (size_t)(m0 + row) * K + kk + c * 8;
                    float4 f0 = *(const float4*)src;
                    float4 f1 = *(const float4*)(src + 4);
                    float fv[8] = {f0.x, f0.y, f0.z, f0.w, f1.x, f1.y, f1.z, f1.w};
                    U128 uh;
#pragma unroll
                    for (int j = 0; j < 8; ++j) uh.s[j] = f2bf(fv[j]);
                    *(uint4*)&Ash[row * LA + c * 8] = uh.v;
                }
            }
#pragma unroll
            for (int i = 0; i < 2; ++i) {
                int s = i * 256 + t;
                int row = s >> 2;
                int cg = (s & 3) ^ ((s >> 3) & 3);
                size_t go = (size_t)(n0 + row) * ldb + kr0 + kk + cg * 8;
                int ls = (i * 256 + (t & ~63)) * 8;
                gld16(bhz + go, &Bsh[ls]);
            }
            __syncthreads();
            v8s ahf[4];
#pragma unroll
            for (int mi = 0; mi < 4; ++mi) {
                int row = wm * 64 + mi * 16 + l15;
                int off;
                if constexpr (AMODE == 0) off = row * LA + ((quad ^ ((row >> 1) & 3)) * 8);
                else                      off = row * LA + quad * 8;
                ahf[mi] = *(const v8s*)&Ash[off];
            }
#pragma unroll
            for (int ni = 0; ni < 4; ++ni) {
                int row = wn * 64 + ni * 16 + l15;
                int off = row * LB + ((quad ^ ((row >> 1) & 3)) * 8);
                v8s bhf = *(const v8s*)&Bsh[off];
#pragma unroll
                for (int mi = 0; mi < 4; ++mi) {
                    if constexpr (DT == 0)
                        acc[mi][ni] = __builtin_amdgcn_mfma_f32_16x16x32_bf16(ahf[mi], bhf, acc[mi][ni], 0, 0, 0);
                    else
                        acc[mi][ni] = __builtin_amdgcn_mfma_f32_16x16x32_f16(as_h(ahf[mi]), as_h(bhf), acc[mi][ni], 0, 0, 0);
                }
            }
        }
    }

    const size_t crow0 = (size_t)zb * cZRows + m0;
#pragma unroll
    for (int ni = 0; ni < 4; ++ni) {
        int n = n0 + wn * 64 + ni * 16 + l15;
        float bv = (ACT > 0) ? bias[n] : 0.f;
        float av = (ACT == 2) ? alpha[n] : 0.f;
#pragma unroll
        for (int mi = 0; mi < 4; ++mi) {
#pragma unroll
            for (int r = 0; r < 4; ++r) {
                int m = wm * 64 + mi * 16 + quad * 4 + r;
                float v = acc[mi][ni][r] + bv;
                if (ACT == 1) v = v > 0.f ? v : 0.f;
                if (ACT == 2) v = v > 0.f ? v : av * v;
                acc[mi][ni][r] = v;
                o_[(crow0 + m) * (size_t)Nout + n] = f2h(v);
            }
        }
    }

    if constexpr (WRT) {
        const int zbT = m0 >> 10;
        const int mloc0 = (m0 & 1023) + wm * 64;
#pragma unroll
        for (int ni = 0; ni < 4; ++ni) {
            int f = n0 + wn * 64 + ni * 16 + l15;
            size_t rowb = (((size_t)zbT * Nout + f) << 10) + mloc0;
#pragma unroll
            for (int mi = 0; mi < 4; ++mi) {
                ushort4 u;
                unsigned short* up = (unsigned short*)&u;
#pragma unroll
                for (int r = 0; r < 4; ++r) up[r] = f2bf(acc[mi][ni][r]);
                *(ushort4*)(th + rowb + mi * 16 + quad * 4) = u;
            }
        }
    }
}

// ---------------------------------------------------------------------------
// Phase-interleaved GEMM, 2 blocks/CU occupancy variant.
//   Tiles: (BM,BN2) in {(256,128),(128,128)}. BK=32. 512 thr = 8 waves.
//   Ring-3 LDS (72/48 KB -> 2 blocks/CU fit 160 KB); counted vmcnt never 0
//   until one-tile-from-end; __launch_bounds__(512,4) forces <=128 VGPR so
//   16 waves/CU are resident -> inter-block overlap hides prologue/epilogue/
//   stage bursts.
// Ring-3 invariant at top of tile tt: tt resident; tt+1 in flight (LPT);
// stage(tt+2) issued now into slot (tt+2)%3 = slot of tt-1, whose ds_reads
// drained (lgkmcnt before MFMAs) before the previous iter barrier; end-of-
// iter wait vmcnt(LPT) <=> tt+1 landed (oldest-first).
template <int ACT, bool TWO, int DT, bool WRT, int BM, int BN2, int NB, bool Z32>
__global__ __launch_bounds__(512, 4) void gemm256(
    const unsigned short* __restrict__ a1, const unsigned short* __restrict__ a2,
    int K1, int K2,
    const unsigned short* __restrict__ b_, int ldb,
    const float* __restrict__ bias, const float* __restrict__ alpha,
    unsigned short* __restrict__ o_, int Nout,
    unsigned short* __restrict__ th,
    size_t aZ, size_t bZ, int cZRows)
{
    constexpr int ASLOT = BM * 32;           // ushorts per A K-tile
    constexpr int BSLOT = BN2 * 32;
    constexpr int SLOT  = ASLOT + BSLOT;
    constexpr int AR    = BM / 128;          // A stage rounds (512thr x 16B)
    constexpr int BR    = BN2 / 128;         // B stage rounds
    constexpr int LPT   = AR + BR;           // gld16 per thread per K-tile
    constexpr int WN    = BN2 / 64;          // waves along N
    constexpr int WM    = 8 / WN;            // waves along M
    constexpr int MREP  = BM / (WM * 16);    // 16x16 frags along M per wave
    constexpr int NPH   = (MREP >= 2) ? MREP / 2 : 1;  // phases per K-tile
    constexpr int NSH   = (NB == 4) ? 2 : 1;
    __shared__ __align__(16) unsigned short lds[3 * SLOT];

    const int t = threadIdx.x;
    const int lane = t & 63, wave = t >> 6;
    const int wm = wave / WN, wn = wave % WN;
    const int l15 = lane & 15, quad = lane >> 4;

    // XCD-locality chunked decode; grid == 512 (64 blocks per XCD)
    const int bx = blockIdx.x;
    const int xcd = bx & 7, loc = bx >> 3;   // loc 0..63
    int zb, mIdx, nIdx;
    if constexpr (Z32) {
        zb = xcd * 4 + (loc >> 4);           // 4 zb per XCD, 16 blocks each
        int l = loc & 15;
        mIdx = l >> NSH;
        nIdx = l & (NB - 1);
    } else {
        constexpr int MC = 32768 / BM;       // m-tiles total
        zb = 0;
        mIdx = xcd * (MC / 8) + (loc >> NSH);
        nIdx = loc & (NB - 1);
    }
    const int m0 = mIdx * BM + (Z32 ? 0 : 0);
    const int n0 = nIdx * BN2;

    const unsigned short* A1 = a1 + (size_t)zb * aZ;
    const unsigned short* A2p = TWO ? (a2 + (size_t)zb * aZ) : nullptr;
    const unsigned short* B = b_ + (size_t)zb * bZ;

    const int NT1 = K1 >> 5;
    const int NTtot = NT1 + (TWO ? (K2 >> 5) : 0);   // >= 8

    // issue part p (0..NPH-1) of tile tt's staging into slot
    auto stage_part = [&](unsigned short* slot, int tt, int p) {
        const unsigned short* abase;
        int astr;
        if constexpr (TWO) {
            if (tt >= NT1) { abase = A2p + ((size_t)(tt - NT1) << 5); astr = K2; }
            else           { abase = A1 + ((size_t)tt << 5); astr = K1; }
        } else {
            abase = A1 + ((size_t)tt << 5); astr = K1;
        }
        auto lda = [&](int i) {
            int s = i * 512 + t;
            int row = s >> 2;
            int cg = (s & 3) ^ ((s >> 3) & 3);            // read-side-matched swizzle
            gld16(abase + (size_t)(m0 + row) * astr + cg * 8,
                  &slot[(i * 512 + (t & ~63)) * 8]);
        };
        auto ldbf = [&](int i) {
            const unsigned short* bbase = B + ((size_t)tt << 5);
            int s = i * 512 + t;
            int row = s >> 2;
            int cg = (s & 3) ^ ((s >> 3) & 3);
            gld16(bbase + (size_t)(n0 + row) * ldb + cg * 8,
                  &slot[ASLOT + (i * 512 + (t & ~63)) * 8]);
        };
        if constexpr (NPH == 1) {
#pragma unroll
            for (int i = 0; i < AR; ++i) lda(i);
#pragma unroll
            for (int i = 0; i < BR; ++i) ldbf(i);
        } else {                              // NPH==2: AR==2, BR==1
            if (p == 0) { lda(0); lda(1); }
            else        { ldbf(0); }
        }
    };
    auto stage_all = [&](unsigned short* slot, int tt) {
#pragma unroll
        for (int p = 0; p < NPH; ++p) stage_part(slot, tt, p);
    };

    v4f acc[MREP][4] = {};

    auto rdA = [&](const unsigned short* slot, int mi) -> v8s {
        int row = wm * (MREP * 16) + mi * 16 + l15;
        return *(const v8s*)&slot[row * 32 + ((quad ^ ((row >> 1) & 3)) * 8)];
    };
    auto rdB = [&](const unsigned short* slot, int ni) -> v8s {
        int row = wn * 64 + ni * 16 + l15;
        return *(const v8s*)&slot[ASLOT + row * 32 + ((quad ^ ((row >> 1) & 3)) * 8)];
    };

    auto wait_lpt = [&]() {
        if constexpr (LPT == 4)      asm volatile("s_waitcnt vmcnt(4)" ::: "memory");
        else if constexpr (LPT == 3) asm volatile("s_waitcnt vmcnt(3)" ::: "memory");
        else                         asm volatile("s_waitcnt vmcnt(2)" ::: "memory");
    };

    // prologue: 2 tiles staged; drain tile 0 (leave tile 1's LPT in flight)
    stage_all(&lds[0], 0);
    stage_all(&lds[SLOT], 1);
    wait_lpt();
    __builtin_amdgcn_s_barrier();
    asm volatile("" ::: "memory");

    int cs = 0;                               // slot index of tile tt
    for (int tt = 0; tt < NTtot; ++tt) {
        unsigned short* slot = &lds[cs * SLOT];
        int ssIdx = cs + 2; if (ssIdx >= 3) ssIdx -= 3;
        unsigned short* sslot = &lds[ssIdx * SLOT];
        const bool st = (tt + 2 < NTtot);
        v8s bf[4];
#pragma unroll
        for (int q = 0; q < NPH; ++q) {
            if (q == 0) {
#pragma unroll
                for (int ni = 0; ni < 4; ++ni) bf[ni] = rdB(slot, ni);
            }
            v8s a0, a1;
            if constexpr (NPH == 1) { a0 = rdA(slot, 0); a1 = rdA(slot, 1); }
            else                    { a0 = rdA(slot, 2 * q); a1 = rdA(slot, 2 * q + 1); }
            if (st) stage_part(sslot, tt + 2, q);
            __builtin_amdgcn_s_barrier();
            asm volatile("" ::: "memory");
            __builtin_amdgcn_s_setprio(1);
            const int mb = (NPH == 1) ? 0 : 2 * q;
#pragma unroll
            for (int ni = 0; ni < 4; ++ni) {
                if constexpr (DT == 0) {
                    acc[mb][ni]     = __builtin_amdgcn_mfma_f32_16x16x32_bf16(a0, bf[ni], acc[mb][ni], 0, 0, 0);
                    acc[mb + 1][ni] = __builtin_amdgcn_mfma_f32_16x16x32_bf16(a1, bf[ni], acc[mb + 1][ni], 0, 0, 0);
                } else {
                    acc[mb][ni]     = __builtin_amdgcn_mfma_f32_16x16x32_f16(as_h(a0), as_h(bf[ni]), acc[mb][ni], 0, 0, 0);
                    acc[mb + 1][ni] = __builtin_amdgcn_mfma_f32_16x16x32_f16(as_h(a1), as_h(bf[ni]), acc[mb + 1][ni], 0, 0, 0);
                }
            }
            __builtin_amdgcn_s_setprio(0);
        }
        if (tt + 1 < NTtot) {
            if (st) wait_lpt();
            else    asm volatile("s_waitcnt vmcnt(0)" ::: "memory");
            __builtin_amdgcn_s_barrier();
            asm volatile("" ::: "memory");
        }
        cs = (cs == 2) ? 0 : cs + 1;
    }

    // ---- epilogue: bias/act folded into acc, f16 normal store
    const size_t crow0 = (size_t)zb * cZRows + m0;
#pragma unroll
    for (int ni = 0; ni < 4; ++ni) {
        int n = n0 + wn * 64 + ni * 16 + l15;
        float bv = (ACT > 0) ? bias[n] : 0.f;
        float av = (ACT == 2) ? alpha[n] : 0.f;
#pragma unroll
        for (int mi = 0; mi < MREP; ++mi) {
#pragma unroll
            for (int r = 0; r < 4; ++r) {
                int m = wm * (MREP * 16) + mi * 16 + quad * 4 + r;
                float v = acc[mi][ni][r] + bv;
                if (ACT == 1) v = v > 0.f ? v : 0.f;
                if (ACT == 2) v = v > 0.f ? v : av * v;
                acc[mi][ni][r] = v;
                o_[(crow0 + m) * (size_t)Nout + n] = f2h(v);
            }
        }
    }

    // ---- fused transposed bf16 store: HT[zbT][f][1024]
    if constexpr (WRT) {
        const int zbT = m0 >> 10;
        const int mloc0 = (m0 & 1023) + wm * (MREP * 16);
#pragma unroll
        for (int ni = 0; ni < 4; ++ni) {
            int f = n0 + wn * 64 + ni * 16 + l15;
            size_t rowb = (((size_t)zbT * Nout + f) << 10) + mloc0;
#pragma unroll
            for (int mi = 0; mi < MREP; ++mi) {
                ushort4 u;
                unsigned short* up = (unsigned short*)&u;
#pragma unroll
                for (int r = 0; r < 4; ++r) up[r] = f2bf(acc[mi][ni][r]);
                *(ushort4*)(th + rowb + mi * 16 + quad * 4) = u;
            }
        }
    }
}

// ---------------------------------------------------------------------------
// pred = H5 @ cW2 + cb2, H5 f16 single plane, fp32 accumulation
__global__ __launch_bounds__(256) void final_gemm(const unsigned short* __restrict__ hh,
                                                  const float* __restrict__ W,
                                                  const float* __restrict__ bias,
                                                  float* __restrict__ out) {
    const int t = threadIdx.x;
    const int m = blockIdx.x * 64 + (t >> 2);
    const int kq = (t & 3) * 64;
    const unsigned short* ph = hh + (size_t)m * 256 + kq;
    float a0 = 0.f, a1 = 0.f;
#pragma unroll
    for (int i = 0; i < 8; ++i) {
        uint4 vh = *(const uint4*)(ph + i * 8);
        const unsigned short* sh = (const unsigned short*)&vh;
#pragma unroll
        for (int j = 0; j < 8; ++j) {
            int k = kq + i * 8 + j;
            float h = h2f(sh[j]);
            a0 += h * W[k * 2];
            a1 += h * W[k * 2 + 1];
        }
    }
    a0 += __shfl_down(a0, 2); a0 += __shfl_down(a0, 1);
    a1 += __shfl_down(a1, 2); a1 += __shfl_down(a1, 1);
    if ((t & 3) == 0) {
        out[(size_t)m * 2] = a0 + bias[0];
        out[(size_t)m * 2 + 1] = a1 + bias[1];
    }
}

// ---------------------------------------------------------------------------
extern "C" void kernel_launch(void* const* d_in, const int* in_sizes, int n_in,
                              void* d_out, int out_size, void* d_ws, size_t ws_size,
                              hipStream_t stream) {
    const float* x   = (const float*)d_in[0];
    const float* adj = (const float*)d_in[1];
    const float* W1  = (const float*)d_in[2];
    const float* b1  = (const float*)d_in[3];
    const float* W2  = (const float*)d_in[4];
    const float* b2  = (const float*)d_in[5];
    const float* W3  = (const float*)d_in[6];
    const float* b3  = (const float*)d_in[7];
    const float* W4  = (const float*)d_in[8];
    const float* b4  = (const float*)d_in[9];
    const float* cW1 = (const float*)d_in[10];
    const float* cb1 = (const float*)d_in[11];
    const float* alp = (const float*)d_in[12];
    const float* cW2 = (const float*)d_in[13];
    const float* cb2 = (const float*)d_in[14];
    float* out = (float*)d_out;

    const size_t P   = 32768ull * 512;       // 16,777,216 ushorts per act plane
    const size_t XP  = 32768ull * 256;       // x f16 plane
    const size_t WT_TOT = 1245184;
    const size_t ADJ = 32ull * 1024 * 1024;

    unsigned short* N1  = (unsigned short*)d_ws;
    unsigned short* N2  = N1 + P;
    unsigned short* N3  = N2 + P;
    unsigned short* Th  = N3 + P;            // transposed activations, bf16
    unsigned short* X16 = Th + P;            // x as f16
    unsigned short* WT  = X16 + XP;          // transposed weights, f16
    unsigned short* SA  = WT + WT_TOT;       // adj bf16

    const size_t o1 = 0, o2 = 262144, o3 = 786432, o4 = 1048576, o5 = 1179648;
    const bool preAdj = ws_size >= (4 * P + XP + WT_TOT + ADJ) * sizeof(unsigned short);

    dim3 blk(256);
    dim3 blk5(512);

    tsplit16<<<dim3(8, 8),  blk, 0, stream>>>(W1,  WT + o1, 512, 512);
    tsplit16<<<dim3(16, 8), blk, 0, stream>>>(W2,  WT + o2, 1024, 512);
    tsplit16<<<dim3(16, 4), blk, 0, stream>>>(W3,  WT + o3, 1024, 256);
    tsplit16<<<dim3(8, 4),  blk, 0, stream>>>(W4,  WT + o4, 512, 256);
    tsplit16<<<dim3(4, 4),  blk, 0, stream>>>(cW1, WT + o5, 256, 256);
    if (preAdj)
        split_hi<<<32768, blk, 0, stream>>>(adj, SA, (int)(ADJ / 4));

    // x -> X16 (f16) + Th (bf16 transposed), single pass over x
    xprep<<<dim3(16, 4, 32), blk, 0, stream>>>(x, Th, X16, 256);

    // agg1 = adj @ x (N=256) -> N2
    if (preAdj)
        gemm256<0, false, 0, false, 128, 128, 2, true><<<512, blk5, 0, stream>>>(
            SA, nullptr, 1024, 0, Th, 1024, nullptr, nullptr,
            N2, 256, nullptr, (size_t)1 << 20, 256ull * 1024, 1024);
    else
        gemm128<0, false, 1, 0, false><<<512, blk, 0, stream>>>(
            adj, nullptr, 1024, 0, Th, 1024, nullptr, nullptr,
            N2, 256, nullptr, (size_t)1 << 20, 256ull * 1024, 1024, 2, 3);

    // dense1 = relu([x|AGG1] @ W1 + b1) (N=512) -> N3, fused H1T -> Th
    gemm256<1, true, 1, true, 256, 128, 4, false><<<512, blk5, 0, stream>>>(
        X16, N2, 256, 256, WT + o1, 512, b1, nullptr,
        N3, 512, Th, 0, 0, 0);

    // agg2 = adj @ H1 (N=512) -> N1
    if (preAdj)
        gemm256<0, false, 0, false, 256, 128, 4, true><<<512, blk5, 0, stream>>>(
            SA, nullptr, 1024, 0, Th, 1024, nullptr, nullptr,
            N1, 512, nullptr, (size_t)1 << 20, 512ull * 1024, 1024);
    else
        gemm128<0, false, 1, 0, false><<<1024, blk, 0, stream>>>(
            adj, nullptr, 1024, 0, Th, 1024, nullptr, nullptr,
            N1, 512, nullptr, (size_t)1 << 20, 512ull * 1024, 1024, 4, 3);

    // dense2 (N=512) -> N2, fused H2T -> Th
    gemm256<1, true, 1, true, 256, 128, 4, false><<<512, blk5, 0, stream>>>(
        N3, N1, 512, 512, WT + o2, 1024, b2, nullptr,
        N2, 512, Th, 0, 0, 0);

    // agg3 = adj @ H2 (N=512) -> N1
    if (preAdj)
        gemm256<0, false, 0, false, 256, 128, 4, true><<<512, blk5, 0, stream>>>(
            SA, nullptr, 1024, 0, Th, 1024, nullptr, nullptr,
            N1, 512, nullptr, (size_t)1 << 20, 512ull * 1024, 1024);
    else
        gemm128<0, false, 1, 0, false><<<1024, blk, 0, stream>>>(
            adj, nullptr, 1024, 0, Th, 1024, nullptr, nullptr,
            N1, 512, nullptr, (size_t)1 << 20, 512ull * 1024, 1024, 4, 3);

    // dense3 (N=256) -> N3, fused H3T -> Th
    gemm256<1, true, 1, true, 128, 128, 2, false><<<512, blk5, 0, stream>>>(
        N2, N1, 512, 512, WT + o3, 1024, b3, nullptr,
        N3, 256, Th, 0, 0, 0);

    // agg4 = adj @ H3 (N=256) -> N1
    if (preAdj)
        gemm256<0, false, 0, false, 128, 128, 2, true><<<512, blk5, 0, stream>>>(
            SA, nullptr, 1024, 0, Th, 1024, nullptr, nullptr,
            N1, 256, nullptr, (size_t)1 << 20, 256ull * 1024, 1024);
    else
        gemm128<0, false, 1, 0, false><<<512, blk, 0, stream>>>(
            adj, nullptr, 1024, 0, Th, 1024, nullptr, nullptr,
            N1, 256, nullptr, (size_t)1 << 20, 256ull * 1024, 1024, 2, 3);

    // dense4 (N=256) -> N2
    gemm256<1, true, 1, false, 128, 128, 2, false><<<512, blk5, 0, stream>>>(
        N3, N1, 256, 256, WT + o4, 512, b4, nullptr,
        N2, 256, nullptr, 0, 0, 0);

    // cls1 = prelu(H4 @ cW1 + cb1) (N=256) -> N3
    gemm256<2, false, 1, false, 128, 128, 2, false><<<512, blk5, 0, stream>>>(
        N2, nullptr, 256, 0, WT + o5, 256, cb1, alp,
        N3, 256, nullptr, 0, 0, 0);

    // final
    final_gemm<<<512, blk, 0, stream>>>(N3, cW2, cb2, out);
}